// Round 2
// baseline (1208.411 us; speedup 1.0000x reference)
//
#include <hip/hip_runtime.h>
#include <hip/hip_bf16.h>

#define FD 128   // IN == HID == 128
#define OD 64    // OUT

typedef __hip_bfloat16 bf16;

__device__ __forceinline__ float b2f(bf16 x) { return __bfloat162float(x); }
__device__ __forceinline__ float ldf(const float* p, size_t i) { return p[i]; }
__device__ __forceinline__ float ldf(const bf16* p, size_t i) { return __bfloat162float(p[i]); }

// ---------- dtype sniffer: bf16 data -> sane exponents; fp32 read as u16 -> garbage ----------
__global__ void k_sniff(const unsigned short* w1raw, unsigned* flag) {
    int t = threadIdx.x;                 // 64 threads
    int insane = 0;
    for (int i = t; i < 128; i += 64) {
        unsigned e = (w1raw[i] >> 7) & 0xFF;
        if (e != 0 && (e < 100 || e > 140)) insane++;
    }
    for (int o = 32; o > 0; o >>= 1) insane += __shfl_down(insane, o);
    if (t == 0) *flag = (insane > 16) ? 1u : 0u;   // 0 = bf16 world, 1 = fp32 world
}

// ---------- degree count ----------
__global__ void k_deg(const int* __restrict__ src, const int* __restrict__ dst,
                      unsigned* __restrict__ deg_s, unsigned* __restrict__ deg_d, int E) {
    int i = blockIdx.x * blockDim.x + threadIdx.x;
    if (i < E) {
        atomicAdd(&deg_s[src[i]], 1u);
        atomicAdd(&deg_d[dst[i]], 1u);
    }
}

// ---------- c = rsqrt(max(deg,1)) ----------
__global__ void k_cnorm(const unsigned* __restrict__ deg_s, const unsigned* __restrict__ deg_d,
                        float* __restrict__ c_src, float* __restrict__ c_dst, int n) {
    int i = blockIdx.x * blockDim.x + threadIdx.x;
    if (i < n) {
        c_src[i] = rsqrtf(fmaxf((float)deg_s[i], 1.0f));
        c_dst[i] = rsqrtf(fmaxf((float)deg_d[i], 1.0f));
    }
}

// ---------- wsum[s] = sum over out-edges of c_dst[dst] ----------
__global__ void k_wsum(const int* __restrict__ src, const int* __restrict__ dst,
                       const float* __restrict__ c_dst, float* __restrict__ wsum, int E) {
    int e = blockIdx.x * blockDim.x + threadIdx.x;
    if (e < E) unsafeAtomicAdd(&wsum[src[e]], c_dst[dst[e]]);
}

// ---------- scan stage 1: per-block sums of in-degree ----------
__global__ void k_scan1(const unsigned* __restrict__ deg, unsigned* __restrict__ bsum, int n) {
    __shared__ unsigned red[256];
    int t = threadIdx.x, i = blockIdx.x * 256 + t;
    red[t] = (i < n) ? deg[i] : 0u;
    __syncthreads();
    for (int o = 128; o > 0; o >>= 1) {
        if (t < o) red[t] += red[t + o];
        __syncthreads();
    }
    if (t == 0) bsum[blockIdx.x] = red[0];
}

// ---------- scan stage 2: exclusive scan of block sums (single block, 512 thr) ----------
__global__ void k_scan2(const unsigned* __restrict__ bsum, unsigned* __restrict__ bpre, int nb) {
    __shared__ unsigned s[512];
    int t = threadIdx.x;
    unsigned v = (t < nb) ? bsum[t] : 0u;
    s[t] = v;
    __syncthreads();
    for (int o = 1; o < 512; o <<= 1) {
        unsigned x = (t >= o) ? s[t - o] : 0u;
        __syncthreads();
        s[t] += x;
        __syncthreads();
    }
    if (t < nb) bpre[t] = s[t] - v;
}

// ---------- scan stage 3: row_ptr + cursor ----------
__global__ void k_scan3(const unsigned* __restrict__ deg, const unsigned* __restrict__ bpre,
                        unsigned* __restrict__ row_ptr, unsigned* __restrict__ cursor,
                        int n, int E) {
    __shared__ unsigned s[256];
    int t = threadIdx.x, i = blockIdx.x * 256 + t;
    unsigned v = (i < n) ? deg[i] : 0u;
    s[t] = v;
    __syncthreads();
    for (int o = 1; o < 256; o <<= 1) {
        unsigned x = (t >= o) ? s[t - o] : 0u;
        __syncthreads();
        s[t] += x;
        __syncthreads();
    }
    unsigned excl = bpre[blockIdx.x] + s[t] - v;
    if (i < n) { row_ptr[i] = excl; cursor[i] = excl; }
    if (blockIdx.x == 0 && t == 0) row_ptr[n] = (unsigned)E;
}

// ---------- CSR fill: col[] = src sorted by dst ----------
__global__ void k_fill(const int* __restrict__ src, const int* __restrict__ dst,
                       unsigned* __restrict__ cursor, unsigned* __restrict__ col, int E) {
    int e = blockIdx.x * blockDim.x + threadIdx.x;
    if (e < E) {
        unsigned p = atomicAdd(&cursor[dst[e]], 1u);
        col[p] = (unsigned)src[e];
    }
}

// ---------- layer1 fused: gather + GEMM + relu + weighted global reduce ----------
// For node d: acc = sum_{s in in(d)} c_src[s]*feat[s]; h = relu(c_dst[d]*(acc@W1) + b1);
// accum128[j] += wsum[d]*c_src[d]*h[j]
template <typename T>
__global__ __launch_bounds__(256) void k_layer1(const unsigned* __restrict__ flag, unsigned want,
                                                const T* __restrict__ feat, const T* __restrict__ W1,
                                                const T* __restrict__ b1,
                                                const float* __restrict__ c_src,
                                                const float* __restrict__ c_dst,
                                                const float* __restrict__ wsum,
                                                const unsigned* __restrict__ row_ptr,
                                                const unsigned* __restrict__ col,
                                                float* __restrict__ accum128, int n) {
    if (*flag != want) return;
    __shared__ bf16 Wl[FD * FD];      // 32 KB
    __shared__ float b1l[FD];
    __shared__ float xs[2][FD];
    __shared__ float part[2][FD];
    int t = threadIdx.x;
    for (int i = t; i < FD * FD; i += 256) Wl[i] = __float2bfloat16(ldf(W1, i));
    if (t < FD) b1l[t] = ldf(b1, t);
    part[t >> 7][t & 127] = 0.0f;
    __syncthreads();

    int j = t & 127, half = t >> 7;
    int base = blockIdx.x * 64;
    for (int p = 0; p < 32; p++) {
        int node = base + p * 2 + half;
        float acc = 0.0f;
        if (node < n) {
            unsigned beg = row_ptr[node], end = row_ptr[node + 1];
            for (unsigned q = beg; q < end; q++) {
                unsigned s = col[q];
                acc += c_src[s] * ldf(feat, (size_t)s * FD + j);
            }
        }
        xs[half][j] = acc;
        __syncthreads();
        float dot = 0.0f;
        #pragma unroll 8
        for (int k = 0; k < FD; k++) dot += xs[half][k] * b2f(Wl[k * FD + j]);
        if (node < n) {
            float h = fmaxf(dot * c_dst[node] + b1l[j], 0.0f);
            part[half][j] += h * wsum[node] * c_src[node];
        }
        __syncthreads();
    }
    if (t < FD) unsafeAtomicAdd(&accum128[t], part[0][t] + part[1][t]);
}

// ---------- final tiny GEMM: out = (accum128/N) @ W2 + b2 ----------
template <typename T, typename TO>
__global__ void k_final(const unsigned* __restrict__ flag, unsigned want,
                        const float* __restrict__ accum128,
                        const T* __restrict__ W2, const T* __restrict__ b2v,
                        TO* __restrict__ out, float invN) {
    if (*flag != want) return;
    int j = threadIdx.x;   // 64 threads
    float acc = 0.0f;
    for (int k = 0; k < FD; k++) acc += accum128[k] * ldf(W2, (size_t)k * OD + j);
    float v = acc * invN + ldf(b2v, j);
    if constexpr (sizeof(TO) == 2) out[j] = __float2bfloat16(v);
    else                           out[j] = (TO)v;
}

extern "C" void kernel_launch(void* const* d_in, const int* in_sizes, int n_in,
                              void* d_out, int out_size, void* d_ws, size_t ws_size,
                              hipStream_t stream) {
    const int* src = (const int*)d_in[1];
    const int* dst = (const int*)d_in[2];
    int N = in_sizes[0] / FD;
    int E = in_sizes[1];

    char* ws = (char*)d_ws;
    unsigned* flag     = (unsigned*)(ws);
    float*    accum128 = (float*)   (ws + 1024);
    unsigned* bsum     = (unsigned*)(ws + 4096);
    unsigned* bpre     = (unsigned*)(ws + 8192);
    unsigned* deg_s    = (unsigned*)(ws + 16384);
    unsigned* deg_d    = (unsigned*)(ws + 524288);
    float*    c_src    = (float*)   (ws + 1048576);
    float*    c_dst    = (float*)   (ws + 1572864);
    float*    wsum     = (float*)   (ws + 2097152);
    unsigned* row_ptr  = (unsigned*)(ws + 2621440);
    unsigned* cursor   = (unsigned*)(ws + 3145728);
    unsigned* col      = (unsigned*)(ws + 3670016);
    // total footprint: 3670016 + E*4 = ~10.1 MB

    hipMemsetAsync(deg_s, 0, (size_t)N * 4, stream);
    hipMemsetAsync(deg_d, 0, (size_t)N * 4, stream);
    hipMemsetAsync(wsum,  0, (size_t)N * 4, stream);
    hipMemsetAsync(accum128, 0, FD * 4, stream);

    int nb = (N + 255) / 256;   // 391 <= 512

    k_sniff<<<1, 64, 0, stream>>>((const unsigned short*)d_in[3], flag);
    k_deg<<<(E + 255) / 256, 256, 0, stream>>>(src, dst, deg_s, deg_d, E);
    k_cnorm<<<nb, 256, 0, stream>>>(deg_s, deg_d, c_src, c_dst, N);
    k_wsum<<<(E + 255) / 256, 256, 0, stream>>>(src, dst, c_dst, wsum, E);
    k_scan1<<<nb, 256, 0, stream>>>(deg_d, bsum, N);
    k_scan2<<<1, 512, 0, stream>>>(bsum, bpre, nb);
    k_scan3<<<nb, 256, 0, stream>>>(deg_d, bpre, row_ptr, cursor, N, E);
    k_fill<<<(E + 255) / 256, 256, 0, stream>>>(src, dst, cursor, col, E);

    int gl1 = (N + 63) / 64;
    k_layer1<bf16><<<gl1, 256, 0, stream>>>(flag, 0u, (const bf16*)d_in[0], (const bf16*)d_in[3],
                                            (const bf16*)d_in[4], c_src, c_dst, wsum,
                                            row_ptr, col, accum128, N);
    k_layer1<float><<<gl1, 256, 0, stream>>>(flag, 1u, (const float*)d_in[0], (const float*)d_in[3],
                                             (const float*)d_in[4], c_src, c_dst, wsum,
                                             row_ptr, col, accum128, N);

    float invN = 1.0f / (float)N;
    k_final<bf16, bf16><<<1, 64, 0, stream>>>(flag, 0u, accum128, (const bf16*)d_in[5],
                                              (const bf16*)d_in[6], (bf16*)d_out, invN);
    k_final<float, float><<<1, 64, 0, stream>>>(flag, 1u, accum128, (const float*)d_in[5],
                                                (const float*)d_in[6], (float*)d_out, invN);
}

// Round 7
// 1207.351 us; speedup vs baseline: 1.0009x; 1.0009x over previous
//
#include <hip/hip_runtime.h>
#include <hip/hip_bf16.h>

#define FD 128   // IN == HID == 128
#define OD 64    // OUT

typedef __hip_bfloat16 bf16;

__device__ __forceinline__ float b2f(bf16 x) { return __bfloat162float(x); }
__device__ __forceinline__ float ldf(const float* p, size_t i) { return p[i]; }
__device__ __forceinline__ float ldf(const bf16* p, size_t i) { return __bfloat162float(p[i]); }

// ---------- dtype sniffer: bf16 data -> sane exponents; fp32 read as u16 -> garbage ----------
__global__ void k_sniff(const unsigned short* w1raw, unsigned* flag) {
    int t = threadIdx.x;                 // 64 threads
    int insane = 0;
    for (int i = t; i < 128; i += 64) {
        unsigned e = (w1raw[i] >> 7) & 0xFF;
        if (e != 0 && (e < 100 || e > 140)) insane++;
    }
    for (int o = 32; o > 0; o >>= 1) insane += __shfl_down(insane, o);
    if (t == 0) *flag = (insane > 16) ? 1u : 0u;   // 0 = bf16 world, 1 = fp32 world
}

// ---------- degree count ----------
__global__ void k_deg(const int* __restrict__ src, const int* __restrict__ dst,
                      unsigned* __restrict__ deg_s, unsigned* __restrict__ deg_d, int E) {
    int i = blockIdx.x * blockDim.x + threadIdx.x;
    if (i < E) {
        atomicAdd(&deg_s[src[i]], 1u);
        atomicAdd(&deg_d[dst[i]], 1u);
    }
}

// ---------- c = rsqrt(max(deg,1)) ----------
__global__ void k_cnorm(const unsigned* __restrict__ deg_s, const unsigned* __restrict__ deg_d,
                        float* __restrict__ c_src, float* __restrict__ c_dst, int n) {
    int i = blockIdx.x * blockDim.x + threadIdx.x;
    if (i < n) {
        c_src[i] = rsqrtf(fmaxf((float)deg_s[i], 1.0f));
        c_dst[i] = rsqrtf(fmaxf((float)deg_d[i], 1.0f));
    }
}

// ---------- wsum[s] = sum over out-edges of c_dst[dst] ----------
__global__ void k_wsum(const int* __restrict__ src, const int* __restrict__ dst,
                       const float* __restrict__ c_dst, float* __restrict__ wsum, int E) {
    int e = blockIdx.x * blockDim.x + threadIdx.x;
    if (e < E) unsafeAtomicAdd(&wsum[src[e]], c_dst[dst[e]]);
}

// ---------- scan stage 1: per-block sums of in-degree ----------
__global__ void k_scan1(const unsigned* __restrict__ deg, unsigned* __restrict__ bsum, int n) {
    __shared__ unsigned red[256];
    int t = threadIdx.x, i = blockIdx.x * 256 + t;
    red[t] = (i < n) ? deg[i] : 0u;
    __syncthreads();
    for (int o = 128; o > 0; o >>= 1) {
        if (t < o) red[t] += red[t + o];
        __syncthreads();
    }
    if (t == 0) bsum[blockIdx.x] = red[0];
}

// ---------- scan stage 2: exclusive scan of block sums (single block, 512 thr) ----------
__global__ void k_scan2(const unsigned* __restrict__ bsum, unsigned* __restrict__ bpre, int nb) {
    __shared__ unsigned s[512];
    int t = threadIdx.x;
    unsigned v = (t < nb) ? bsum[t] : 0u;
    s[t] = v;
    __syncthreads();
    for (int o = 1; o < 512; o <<= 1) {
        unsigned x = (t >= o) ? s[t - o] : 0u;
        __syncthreads();
        s[t] += x;
        __syncthreads();
    }
    if (t < nb) bpre[t] = s[t] - v;
}

// ---------- scan stage 3: row_ptr + cursor ----------
__global__ void k_scan3(const unsigned* __restrict__ deg, const unsigned* __restrict__ bpre,
                        unsigned* __restrict__ row_ptr, unsigned* __restrict__ cursor,
                        int n, int E) {
    __shared__ unsigned s[256];
    int t = threadIdx.x, i = blockIdx.x * 256 + t;
    unsigned v = (i < n) ? deg[i] : 0u;
    s[t] = v;
    __syncthreads();
    for (int o = 1; o < 256; o <<= 1) {
        unsigned x = (t >= o) ? s[t - o] : 0u;
        __syncthreads();
        s[t] += x;
        __syncthreads();
    }
    unsigned excl = bpre[blockIdx.x] + s[t] - v;
    if (i < n) { row_ptr[i] = excl; cursor[i] = excl; }
    if (blockIdx.x == 0 && t == 0) row_ptr[n] = (unsigned)E;
}

// ---------- CSR fill: col[] = src sorted by dst ----------
__global__ void k_fill(const int* __restrict__ src, const int* __restrict__ dst,
                       unsigned* __restrict__ cursor, unsigned* __restrict__ col, int E) {
    int e = blockIdx.x * blockDim.x + threadIdx.x;
    if (e < E) {
        unsigned p = atomicAdd(&cursor[dst[e]], 1u);
        col[p] = (unsigned)src[e];
    }
}

// ---------- layer1 fused: gather + GEMM + relu + weighted global reduce ----------
// For node d: acc = sum_{s in in(d)} c_src[s]*feat[s]; h = relu(c_dst[d]*(acc@W1) + b1);
// accum128[j] += wsum[d]*c_src[d]*h[j]
template <typename T>
__global__ __launch_bounds__(256) void k_layer1(const unsigned* __restrict__ flag, unsigned want,
                                                const T* __restrict__ feat, const T* __restrict__ W1,
                                                const T* __restrict__ b1,
                                                const float* __restrict__ c_src,
                                                const float* __restrict__ c_dst,
                                                const float* __restrict__ wsum,
                                                const unsigned* __restrict__ row_ptr,
                                                const unsigned* __restrict__ col,
                                                float* __restrict__ accum128, int n) {
    if (*flag != want) return;
    __shared__ bf16 Wl[FD * FD];      // 32 KB
    __shared__ float b1l[FD];
    __shared__ float xs[2][FD];
    __shared__ float part[2][FD];
    int t = threadIdx.x;
    for (int i = t; i < FD * FD; i += 256) Wl[i] = __float2bfloat16(ldf(W1, i));
    if (t < FD) b1l[t] = ldf(b1, t);
    part[t >> 7][t & 127] = 0.0f;
    __syncthreads();

    int j = t & 127, half = t >> 7;
    int base = blockIdx.x * 64;
    for (int p = 0; p < 32; p++) {
        int node = base + p * 2 + half;
        float acc = 0.0f;
        if (node < n) {
            unsigned beg = row_ptr[node], end = row_ptr[node + 1];
            for (unsigned q = beg; q < end; q++) {
                unsigned s = col[q];
                acc += c_src[s] * ldf(feat, (size_t)s * FD + j);
            }
        }
        xs[half][j] = acc;
        __syncthreads();
        float dot = 0.0f;
        #pragma unroll 8
        for (int k = 0; k < FD; k++) dot += xs[half][k] * b2f(Wl[k * FD + j]);
        if (node < n) {
            float h = fmaxf(dot * c_dst[node] + b1l[j], 0.0f);
            part[half][j] += h * wsum[node] * c_src[node];
        }
        __syncthreads();
    }
    if (t < FD) unsafeAtomicAdd(&accum128[t], part[0][t] + part[1][t]);
}

// ---------- final tiny GEMM: out = (accum128/N) @ W2 + b2 ----------
template <typename T, typename TO>
__global__ void k_final(const unsigned* __restrict__ flag, unsigned want,
                        const float* __restrict__ accum128,
                        const T* __restrict__ W2, const T* __restrict__ b2v,
                        TO* __restrict__ out, float invN) {
    if (*flag != want) return;
    int j = threadIdx.x;   // 64 threads
    float acc = 0.0f;
    for (int k = 0; k < FD; k++) acc += accum128[k] * ldf(W2, (size_t)k * OD + j);
    float v = acc * invN + ldf(b2v, j);
    if constexpr (sizeof(TO) == 2) out[j] = __float2bfloat16(v);
    else                           out[j] = (TO)v;
}

extern "C" void kernel_launch(void* const* d_in, const int* in_sizes, int n_in,
                              void* d_out, int out_size, void* d_ws, size_t ws_size,
                              hipStream_t stream) {
    const int* src = (const int*)d_in[1];
    const int* dst = (const int*)d_in[2];
    int N = in_sizes[0] / FD;
    int E = in_sizes[1];

    char* ws = (char*)d_ws;
    unsigned* flag     = (unsigned*)(ws);
    float*    accum128 = (float*)   (ws + 1024);
    unsigned* bsum     = (unsigned*)(ws + 4096);
    unsigned* bpre     = (unsigned*)(ws + 8192);
    unsigned* deg_s    = (unsigned*)(ws + 16384);
    unsigned* deg_d    = (unsigned*)(ws + 524288);
    float*    c_src    = (float*)   (ws + 1048576);
    float*    c_dst    = (float*)   (ws + 1572864);
    float*    wsum     = (float*)   (ws + 2097152);
    unsigned* row_ptr  = (unsigned*)(ws + 2621440);
    unsigned* cursor   = (unsigned*)(ws + 3145728);
    unsigned* col      = (unsigned*)(ws + 3670016);
    // total footprint: 3670016 + E*4 = ~10.1 MB

    hipMemsetAsync(deg_s, 0, (size_t)N * 4, stream);
    hipMemsetAsync(deg_d, 0, (size_t)N * 4, stream);
    hipMemsetAsync(wsum,  0, (size_t)N * 4, stream);
    hipMemsetAsync(accum128, 0, FD * 4, stream);

    int nb = (N + 255) / 256;   // 391 <= 512

    k_sniff<<<1, 64, 0, stream>>>((const unsigned short*)d_in[3], flag);
    k_deg<<<(E + 255) / 256, 256, 0, stream>>>(src, dst, deg_s, deg_d, E);
    k_cnorm<<<nb, 256, 0, stream>>>(deg_s, deg_d, c_src, c_dst, N);
    k_wsum<<<(E + 255) / 256, 256, 0, stream>>>(src, dst, c_dst, wsum, E);
    k_scan1<<<nb, 256, 0, stream>>>(deg_d, bsum, N);
    k_scan2<<<1, 512, 0, stream>>>(bsum, bpre, nb);
    k_scan3<<<nb, 256, 0, stream>>>(deg_d, bpre, row_ptr, cursor, N, E);
    k_fill<<<(E + 255) / 256, 256, 0, stream>>>(src, dst, cursor, col, E);

    int gl1 = (N + 63) / 64;
    k_layer1<bf16><<<gl1, 256, 0, stream>>>(flag, 0u, (const bf16*)d_in[0], (const bf16*)d_in[3],
                                            (const bf16*)d_in[4], c_src, c_dst, wsum,
                                            row_ptr, col, accum128, N);
    k_layer1<float><<<gl1, 256, 0, stream>>>(flag, 1u, (const float*)d_in[0], (const float*)d_in[3],
                                             (const float*)d_in[4], c_src, c_dst, wsum,
                                             row_ptr, col, accum128, N);

    float invN = 1.0f / (float)N;
    k_final<bf16, bf16><<<1, 64, 0, stream>>>(flag, 0u, accum128, (const bf16*)d_in[5],
                                              (const bf16*)d_in[6], (bf16*)d_out, invN);
    k_final<float, float><<<1, 64, 0, stream>>>(flag, 1u, accum128, (const float*)d_in[5],
                                                (const float*)d_in[6], (float*)d_out, invN);
}

// Round 8
// 851.584 us; speedup vs baseline: 1.4190x; 1.4178x over previous
//
#include <hip/hip_runtime.h>
#include <hip/hip_bf16.h>

#define FD 128   // IN == HID == 128
#define OD 64    // OUT

typedef __hip_bfloat16 bf16;

__device__ __forceinline__ float b2f(bf16 x) { return __bfloat162float(x); }
__device__ __forceinline__ float ldf(const float* p, size_t i) { return p[i]; }
__device__ __forceinline__ float ldf(const bf16* p, size_t i) { return __bfloat162float(p[i]); }

// ---------- dtype sniffer: bf16 data -> sane exponents; fp32 read as u16 -> garbage ----------
__global__ void k_sniff(const unsigned short* w1raw, unsigned* flag) {
    int t = threadIdx.x;                 // 64 threads
    int insane = 0;
    for (int i = t; i < 128; i += 64) {
        unsigned e = (w1raw[i] >> 7) & 0xFF;
        if (e != 0 && (e < 100 || e > 140)) insane++;
    }
    for (int o = 32; o > 0; o >>= 1) insane += __shfl_down(insane, o);
    if (t == 0) *flag = (insane > 16) ? 1u : 0u;   // 0 = bf16 world, 1 = fp32 world
}

// ---------- degree count ----------
__global__ void k_deg(const int* __restrict__ src, const int* __restrict__ dst,
                      unsigned* __restrict__ deg_s, unsigned* __restrict__ deg_d, int E) {
    int i = blockIdx.x * blockDim.x + threadIdx.x;
    if (i < E) {
        atomicAdd(&deg_s[src[i]], 1u);
        atomicAdd(&deg_d[dst[i]], 1u);
    }
}

// ---------- c = rsqrt(max(deg,1)) ----------
__global__ void k_cnorm(const unsigned* __restrict__ deg_s, const unsigned* __restrict__ deg_d,
                        float* __restrict__ c_src, float* __restrict__ c_dst, int n) {
    int i = blockIdx.x * blockDim.x + threadIdx.x;
    if (i < n) {
        c_src[i] = rsqrtf(fmaxf((float)deg_s[i], 1.0f));
        c_dst[i] = rsqrtf(fmaxf((float)deg_d[i], 1.0f));
    }
}

// ---------- wsum[s] = sum over out-edges of c_dst[dst] ----------
__global__ void k_wsum(const int* __restrict__ src, const int* __restrict__ dst,
                       const float* __restrict__ c_dst, float* __restrict__ wsum, int E) {
    int e = blockIdx.x * blockDim.x + threadIdx.x;
    if (e < E) unsafeAtomicAdd(&wsum[src[e]], c_dst[dst[e]]);
}

// ---------- scan stage 1: per-block sums of in-degree ----------
__global__ void k_scan1(const unsigned* __restrict__ deg, unsigned* __restrict__ bsum, int n) {
    __shared__ unsigned red[256];
    int t = threadIdx.x, i = blockIdx.x * 256 + t;
    red[t] = (i < n) ? deg[i] : 0u;
    __syncthreads();
    for (int o = 128; o > 0; o >>= 1) {
        if (t < o) red[t] += red[t + o];
        __syncthreads();
    }
    if (t == 0) bsum[blockIdx.x] = red[0];
}

// ---------- scan stage 2: exclusive scan of block sums (single block, 512 thr) ----------
__global__ void k_scan2(const unsigned* __restrict__ bsum, unsigned* __restrict__ bpre, int nb) {
    __shared__ unsigned s[512];
    int t = threadIdx.x;
    unsigned v = (t < nb) ? bsum[t] : 0u;
    s[t] = v;
    __syncthreads();
    for (int o = 1; o < 512; o <<= 1) {
        unsigned x = (t >= o) ? s[t - o] : 0u;
        __syncthreads();
        s[t] += x;
        __syncthreads();
    }
    if (t < nb) bpre[t] = s[t] - v;
}

// ---------- scan stage 3: row_ptr + cursor ----------
__global__ void k_scan3(const unsigned* __restrict__ deg, const unsigned* __restrict__ bpre,
                        unsigned* __restrict__ row_ptr, unsigned* __restrict__ cursor,
                        int n, int E) {
    __shared__ unsigned s[256];
    int t = threadIdx.x, i = blockIdx.x * 256 + t;
    unsigned v = (i < n) ? deg[i] : 0u;
    s[t] = v;
    __syncthreads();
    for (int o = 1; o < 256; o <<= 1) {
        unsigned x = (t >= o) ? s[t - o] : 0u;
        __syncthreads();
        s[t] += x;
        __syncthreads();
    }
    unsigned excl = bpre[blockIdx.x] + s[t] - v;
    if (i < n) { row_ptr[i] = excl; cursor[i] = excl; }
    if (blockIdx.x == 0 && t == 0) row_ptr[n] = (unsigned)E;
}

// ---------- CSR fill: col[] = src sorted by dst ----------
__global__ void k_fill(const int* __restrict__ src, const int* __restrict__ dst,
                       unsigned* __restrict__ cursor, unsigned* __restrict__ col, int E) {
    int e = blockIdx.x * blockDim.x + threadIdx.x;
    if (e < E) {
        unsigned p = atomicAdd(&cursor[dst[e]], 1u);
        col[p] = (unsigned)src[e];
    }
}

// ---------- layer1 fused: gather + GEMM + relu + weighted global reduce ----------
// SINGLE CHANGE vs round 7: gather loop unrolled x4 (scalar loads, bounds-guarded).
template <typename T>
__global__ __launch_bounds__(256) void k_layer1(const unsigned* __restrict__ flag, unsigned want,
                                                const T* __restrict__ feat, const T* __restrict__ W1,
                                                const T* __restrict__ b1,
                                                const float* __restrict__ c_src,
                                                const float* __restrict__ c_dst,
                                                const float* __restrict__ wsum,
                                                const unsigned* __restrict__ row_ptr,
                                                const unsigned* __restrict__ col,
                                                float* __restrict__ accum128, int n) {
    if (*flag != want) return;
    __shared__ bf16 Wl[FD * FD];      // 32 KB
    __shared__ float b1l[FD];
    __shared__ float xs[2][FD];
    __shared__ float part[2][FD];
    int t = threadIdx.x;
    for (int i = t; i < FD * FD; i += 256) Wl[i] = __float2bfloat16(ldf(W1, i));
    if (t < FD) b1l[t] = ldf(b1, t);
    part[t >> 7][t & 127] = 0.0f;
    __syncthreads();

    int j = t & 127, half = t >> 7;
    int base = blockIdx.x * 64;
    for (int p = 0; p < 32; p++) {
        int node = base + p * 2 + half;
        float acc = 0.0f;
        if (node < n) {
            unsigned beg = row_ptr[node], end = row_ptr[node + 1];
            unsigned q = beg;
            for (; q + 4 <= end; q += 4) {   // x4: four independent gather loads in flight
                unsigned s0 = col[q], s1 = col[q + 1], s2 = col[q + 2], s3 = col[q + 3];
                float f0 = ldf(feat, (size_t)s0 * FD + j);
                float f1 = ldf(feat, (size_t)s1 * FD + j);
                float f2 = ldf(feat, (size_t)s2 * FD + j);
                float f3 = ldf(feat, (size_t)s3 * FD + j);
                acc += c_src[s0] * f0 + c_src[s1] * f1 + c_src[s2] * f2 + c_src[s3] * f3;
            }
            for (; q < end; q++) {
                unsigned s = col[q];
                acc += c_src[s] * ldf(feat, (size_t)s * FD + j);
            }
        }
        xs[half][j] = acc;
        __syncthreads();
        float dot = 0.0f;
        #pragma unroll 8
        for (int k = 0; k < FD; k++) dot += xs[half][k] * b2f(Wl[k * FD + j]);
        if (node < n) {
            float h = fmaxf(dot * c_dst[node] + b1l[j], 0.0f);
            part[half][j] += h * wsum[node] * c_src[node];
        }
        __syncthreads();
    }
    if (t < FD) unsafeAtomicAdd(&accum128[t], part[0][t] + part[1][t]);
}

// ---------- final tiny GEMM: out = (accum128/N) @ W2 + b2 ----------
template <typename T, typename TO>
__global__ void k_final(const unsigned* __restrict__ flag, unsigned want,
                        const float* __restrict__ accum128,
                        const T* __restrict__ W2, const T* __restrict__ b2v,
                        TO* __restrict__ out, float invN) {
    if (*flag != want) return;
    int j = threadIdx.x;   // 64 threads
    float acc = 0.0f;
    for (int k = 0; k < FD; k++) acc += accum128[k] * ldf(W2, (size_t)k * OD + j);
    float v = acc * invN + ldf(b2v, j);
    if constexpr (sizeof(TO) == 2) out[j] = __float2bfloat16(v);
    else                           out[j] = (TO)v;
}

extern "C" void kernel_launch(void* const* d_in, const int* in_sizes, int n_in,
                              void* d_out, int out_size, void* d_ws, size_t ws_size,
                              hipStream_t stream) {
    const int* src = (const int*)d_in[1];
    const int* dst = (const int*)d_in[2];
    int N = in_sizes[0] / FD;
    int E = in_sizes[1];

    char* ws = (char*)d_ws;
    unsigned* flag     = (unsigned*)(ws);
    float*    accum128 = (float*)   (ws + 1024);
    unsigned* bsum     = (unsigned*)(ws + 4096);
    unsigned* bpre     = (unsigned*)(ws + 8192);
    unsigned* deg_s    = (unsigned*)(ws + 16384);
    unsigned* deg_d    = (unsigned*)(ws + 524288);
    float*    c_src    = (float*)   (ws + 1048576);
    float*    c_dst    = (float*)   (ws + 1572864);
    float*    wsum     = (float*)   (ws + 2097152);
    unsigned* row_ptr  = (unsigned*)(ws + 2621440);
    unsigned* cursor   = (unsigned*)(ws + 3145728);
    unsigned* col      = (unsigned*)(ws + 3670016);
    // total footprint: 3670016 + E*4 = ~10.1 MB

    hipMemsetAsync(deg_s, 0, (size_t)N * 4, stream);
    hipMemsetAsync(deg_d, 0, (size_t)N * 4, stream);
    hipMemsetAsync(wsum,  0, (size_t)N * 4, stream);
    hipMemsetAsync(accum128, 0, FD * 4, stream);

    int nb = (N + 255) / 256;   // 391 <= 512

    k_sniff<<<1, 64, 0, stream>>>((const unsigned short*)d_in[3], flag);
    k_deg<<<(E + 255) / 256, 256, 0, stream>>>(src, dst, deg_s, deg_d, E);
    k_cnorm<<<nb, 256, 0, stream>>>(deg_s, deg_d, c_src, c_dst, N);
    k_wsum<<<(E + 255) / 256, 256, 0, stream>>>(src, dst, c_dst, wsum, E);
    k_scan1<<<nb, 256, 0, stream>>>(deg_d, bsum, N);
    k_scan2<<<1, 512, 0, stream>>>(bsum, bpre, nb);
    k_scan3<<<nb, 256, 0, stream>>>(deg_d, bpre, row_ptr, cursor, N, E);
    k_fill<<<(E + 255) / 256, 256, 0, stream>>>(src, dst, cursor, col, E);

    int gl1 = (N + 63) / 64;
    k_layer1<bf16><<<gl1, 256, 0, stream>>>(flag, 0u, (const bf16*)d_in[0], (const bf16*)d_in[3],
                                            (const bf16*)d_in[4], c_src, c_dst, wsum,
                                            row_ptr, col, accum128, N);
    k_layer1<float><<<gl1, 256, 0, stream>>>(flag, 1u, (const float*)d_in[0], (const float*)d_in[3],
                                             (const float*)d_in[4], c_src, c_dst, wsum,
                                             row_ptr, col, accum128, N);

    float invN = 1.0f / (float)N;
    k_final<bf16, bf16><<<1, 64, 0, stream>>>(flag, 0u, accum128, (const bf16*)d_in[5],
                                              (const bf16*)d_in[6], (bf16*)d_out, invN);
    k_final<float, float><<<1, 64, 0, stream>>>(flag, 1u, accum128, (const float*)d_in[5],
                                                (const float*)d_in[6], (float*)d_out, invN);
}